// Round 17
// baseline (522.793 us; speedup 1.0000x reference)
//
#include <hip/hip_runtime.h>

// B=4096, ID=2048, OD=1024. 4-level pyramidal LSTM, f32 I/O.
// r17: GEMM = 256x256 tile, 1024 threads (16 waves = 4 waves/SIMD — all prior
// variants were 2/SIMD), wave grid 4m x 4n (64x64/wave, acc 64 VGPR), frozen
// r8/r14 2-phase counted-vmcnt schedule, vmcnt(2) invariant, T1/T2/T5.
// Two-segment A (A0=flat spec, A1=compact hb). LSTM cell fused in epilogue via
// gate-interleaved weight permutation (W row p <- q*H+o, p=64*(o>>4)+16*q+(o&15)).

typedef __bf16 bf16x8 __attribute__((ext_vector_type(8)));
typedef float f32x4 __attribute__((ext_vector_type(4)));
typedef unsigned short u16x4 __attribute__((ext_vector_type(4)));
typedef unsigned short u16x8 __attribute__((ext_vector_type(8)));

#define AS1 __attribute__((address_space(1)))
#define AS3 __attribute__((address_space(3)))

__device__ __forceinline__ unsigned short f2bf(float f) {
    union { float f; unsigned int i; } v; v.f = f;
    unsigned int r = v.i + 0x7fffu + ((v.i >> 16) & 1u);
    return (unsigned short)(r >> 16);
}
__device__ __forceinline__ float bf2f(unsigned short u) {
    union { unsigned int i; float f; } v; v.i = ((unsigned int)u) << 16; return v.f;
}
__device__ __forceinline__ float sigm(float x) { return 1.f / (1.f + __expf(-x)); }
__device__ __forceinline__ float tanh_(float x) { float e = __expf(2.f * x); return 1.f - 2.f / (e + 1.f); }

// ---------------- merged prep: spec f32->bf16 | weight convert+gate-permute | biases
struct PSeg { const float* src; unsigned short* dst; long g0; int H; int kshift; int dstld; int dstcol; };
struct PArgs {
    PSeg s[7];
    const float* spec; unsigned short* sB;
    const float *bi1, *bh1, *bi2, *bh2, *bi3, *bh3, *bi4, *bh4;
    float *bs1, *bs2, *bs3, *bs4;
};

__global__ __launch_bounds__(256) void prep_all(PArgs pa)
{
    const long NS = 2097152;              // spec u16x4 granules (4096*2048/4)
    const long NP = 4161536;              // permW granules
    const long total = NS + NP + 7680;    // + bias elements
    const long stride = (long)gridDim.x * blockDim.x;
    for (long gi = (long)blockIdx.x * blockDim.x + threadIdx.x; gi < total; gi += stride) {
        if (gi < NS) {
            const float4 v = ((const float4*)pa.spec)[gi];
            u16x4 o; o.x = f2bf(v.x); o.y = f2bf(v.y); o.z = f2bf(v.z); o.w = f2bf(v.w);
            ((u16x4*)pa.sB)[gi] = o;
        } else if (gi < NS + NP) {
            const long gp = gi - NS;
            int si = 0;
#pragma unroll
            for (int k = 1; k < 7; ++k) si += (gp >= pa.s[k].g0);
            const PSeg sg = pa.s[si];
            const long i = gp - sg.g0;
            const int kq = 1 << sg.kshift;
            const int p = (int)(i >> sg.kshift);
            const int kk = ((int)i & (kq - 1)) << 2;
            const int o = ((p >> 6) << 4) | (p & 15);
            const int q = (p >> 4) & 3;
            const long r = (long)q * sg.H + o;
            const float4 v = *(const float4*)(sg.src + (r << (sg.kshift + 2)) + kk);
            u16x4 wv; wv.x = f2bf(v.x); wv.y = f2bf(v.y); wv.z = f2bf(v.z); wv.w = f2bf(v.w);
            *(u16x4*)(sg.dst + (long)p * sg.dstld + sg.dstcol + kk) = wv;
        } else {
            const int i = (int)(gi - NS - NP);
            const float *bih, *bhh; float* dst; int H, j;
            if (i < 4096)      { bih = pa.bi1; bhh = pa.bh1; dst = pa.bs1; H = 1024; j = i; }
            else if (i < 6144) { bih = pa.bi2; bhh = pa.bh2; dst = pa.bs2; H = 512;  j = i - 4096; }
            else if (i < 7168) { bih = pa.bi3; bhh = pa.bh3; dst = pa.bs3; H = 256;  j = i - 6144; }
            else               { bih = pa.bi4; bhh = pa.bh4; dst = pa.bs4; H = 128;  j = i - 7168; }
            const int o = ((j >> 6) << 4) | (j & 15);
            const int q = (j >> 4) & 3;
            dst[j] = bih[q * H + o] + bhh[q * H + o];
        }
    }
}

#define GLL(gsrc, loff) __builtin_amdgcn_global_load_lds(                                   \
    (const AS1 void*)(gsrc), (AS3 void*)(lds + (loff)), 16, 0, 0)

#define FENCE asm volatile("" ::: "memory")

// stage A K-tile tts (both 128-row halves) into LDS buffer qq; 2 GLLs
#define STAGE_A(tts, qq)                                                                    \
    { if ((tts) < nk0) {                                                                    \
        const size_t ko = (size_t)(tts) * 64;                                               \
        GLL(A0 + a0off0 + ko, ((qq) << 16) + sd);                                           \
        GLL(A0 + a0off1 + ko, ((qq) << 16) + 16384 + sd);                                   \
    } else {                                                                                \
        const size_t ko = (size_t)((tts) - nk0) * 64;                                       \
        GLL(A1 + a1off0 + ko, ((qq) << 16) + sd);                                           \
        GLL(A1 + a1off1 + ko, ((qq) << 16) + 16384 + sd);                                   \
    } }

#define STAGE_B(tts, qq)                                                                    \
    { const size_t ko = (size_t)(tts) * 64;                                                 \
        GLL(W + boff0 + ko, ((qq) << 16) + 32768 + sd);                                     \
        GLL(W + boff1 + ko, ((qq) << 16) + 49152 + sd); }

// cluster: 2 mi-rows x all 4 ni (16 MFMA)
#define CLUSTER(MI, AF)                                                                     \
    { _Pragma("unroll") for (int mi = 0; mi < 2; ++mi) {                                    \
        _Pragma("unroll") for (int ni = 0; ni < 2; ++ni) {                                  \
            acc[(MI)+mi][ni] = __builtin_amdgcn_mfma_f32_16x16x32_bf16(                     \
                AF[mi][0], bF0[ni][0], acc[(MI)+mi][ni], 0, 0, 0);                          \
            acc[(MI)+mi][ni] = __builtin_amdgcn_mfma_f32_16x16x32_bf16(                     \
                AF[mi][1], bF0[ni][1], acc[(MI)+mi][ni], 0, 0, 0);                          \
            acc[(MI)+mi][ni+2] = __builtin_amdgcn_mfma_f32_16x16x32_bf16(                   \
                AF[mi][0], bF1[ni][0], acc[(MI)+mi][ni+2], 0, 0, 0);                        \
            acc[(MI)+mi][ni+2] = __builtin_amdgcn_mfma_f32_16x16x32_bf16(                   \
                AF[mi][1], bF1[ni][1], acc[(MI)+mi][ni+2], 0, 0, 0);                        \
    } } }

template<bool HAS_CIN, bool LAST>
__global__ __launch_bounds__(1024, 1) void gemm16(
    const unsigned short* __restrict__ A0, const unsigned short* __restrict__ A1,
    const int K0, const int K1,
    const unsigned short* __restrict__ W,
    const float* __restrict__ bsum, const unsigned short* __restrict__ Cin,
    float* __restrict__ HoutF, unsigned short* __restrict__ HoutB,
    unsigned short* __restrict__ CoutB, const int H)
{
    __shared__ __align__(16) char lds[131072];
    const int t = threadIdx.x;
    const int w = t >> 6, l = t & 63;
    const int wr = w >> 2, wc = w & 3;                 // 4m x 4n waves, 64x64 each
    const int K = K0 + K1;
    const int nk0 = K0 >> 6;

    // T1: bijective XCD swizzle (nwg = 256 for all levels); bx-major
    const int GX = gridDim.x, GY = gridDim.y;
    const int nwg = GX * GY;
    const int bid = (int)blockIdx.y * GX + (int)blockIdx.x;
    const int swz = (bid & 7) * (nwg >> 3) + (bid >> 3);
    const int m0 = (swz / GY) * 256, n0 = (swz % GY) * 256;

    // staging: thread t covers row (t>>3) of each 128-row half, swizzled col granule
    const int colsw = ((t & 7) ^ ((t >> 3) & 7)) * 8;
    const int arow = m0 + (t >> 3);
    const size_t a0off0 = (size_t)arow * K0 + colsw;
    const size_t a0off1 = a0off0 + (size_t)128 * K0;
    const size_t a1off0 = (size_t)arow * K1 + colsw;
    const size_t a1off1 = a1off0 + (size_t)128 * K1;
    const size_t boff0 = (size_t)(n0 + (t >> 3)) * K + colsw;
    const size_t boff1 = boff0 + (size_t)128 * K;
    const int sd = t * 16;                             // 16KB per GLL region

    const int lr128 = (l & 15) * 128;
    const int sw0 = (((l >> 4)    ) ^ (l & 7)) * 16;   // swizzled ds_read granules
    const int sw1 = (((l >> 4) + 4) ^ (l & 7)) * 16;

    f32x4 acc[4][4];
#pragma unroll
    for (int i = 0; i < 4; ++i)
#pragma unroll
        for (int j = 0; j < 4; ++j) acc[i][j] = (f32x4){0.f, 0.f, 0.f, 0.f};

    const int NT = K >> 6;   // >= 4 for all levels; prologue tiles 0,1 in seg0

    // ---- prologue: A(0), B(0) -> buf0; B(1) -> buf1 (A(1) staged in iter 0)
    STAGE_A(0, 0);
    STAGE_B(0, 0);
    STAGE_B(1, 1);

    bf16x8 aLo[2][2], aHi[2][2], bF0[2][2], bF1[2][2];

    for (int tt = 0; tt < NT; ++tt) {
        const int q = tt & 1, qn = q ^ 1;
        const int rbA = (q << 16) + wr * 8192 + lr128;
        const int rbB = (q << 16) + 32768 + wc * 8192 + lr128;
        const bool st1 = (tt + 1 < NT), st2 = (tt + 2 < NT);

        // top rendezvous: A(t),B(t) landed; B(t+1)'s 2 GLLs may stay in flight
        if (st1) { asm volatile("s_waitcnt vmcnt(2)" ::: "memory"); }
        else     { asm volatile("s_waitcnt vmcnt(0)" ::: "memory"); }
        __builtin_amdgcn_s_barrier();
        FENCE;

        // reads for cluster1: aLo (mi 0,1) + ALL B frags
#pragma unroll
        for (int mi = 0; mi < 2; ++mi) {
            aLo[mi][0] = *(const bf16x8*)(lds + rbA + mi * 2048 + sw0);
            aLo[mi][1] = *(const bf16x8*)(lds + rbA + mi * 2048 + sw1);
        }
#pragma unroll
        for (int ni = 0; ni < 2; ++ni) {
            bF0[ni][0] = *(const bf16x8*)(lds + rbB + ni * 2048 + sw0);
            bF0[ni][1] = *(const bf16x8*)(lds + rbB + ni * 2048 + sw1);
            bF1[ni][0] = *(const bf16x8*)(lds + rbB + 4096 + ni * 2048 + sw0);
            bF1[ni][1] = *(const bf16x8*)(lds + rbB + 4096 + ni * 2048 + sw1);
        }
        if (st1) { STAGE_A(tt + 1, qn); }                // other buffer, safe
#pragma unroll
        for (int mi = 0; mi < 2; ++mi) {                 // aHi drains under cluster1
            aHi[mi][0] = *(const bf16x8*)(lds + rbA + 4096 + mi * 2048 + sw0);
            aHi[mi][1] = *(const bf16x8*)(lds + rbA + 4096 + mi * 2048 + sw1);
        }

        // cluster1 (mi 0,1): consumes bF0 AND bF1 -> B reads served by mid-barrier
        __builtin_amdgcn_s_setprio(1);
        CLUSTER(0, aLo);
        __builtin_amdgcn_s_setprio(0);
        __builtin_amdgcn_s_barrier();
        FENCE;

        // cluster2 (mi 2,3): stage B(t+2) -> q (B region of q dead), MFMA with aHi
        if (st2) { STAGE_B(tt + 2, q); }
        __builtin_amdgcn_s_setprio(1);
        CLUSTER(2, aHi);
        __builtin_amdgcn_s_setprio(0);
    }

    // ---- fused LSTM-cell epilogue: wave's 64-col group = 4 gates x 16 outputs
    const int ocol = (n0 >> 6) * 16 + wc * 16 + (l & 15);
    const int bb = n0 + wc * 64 + (l & 15);
    const float b0 = bsum[bb], b1 = bsum[bb + 16], b2 = bsum[bb + 32], b3 = bsum[bb + 48];
    const int mrow0 = m0 + wr * 64 + (l >> 4) * 4;
#pragma unroll
    for (int mi = 0; mi < 4; ++mi)
#pragma unroll
        for (int j = 0; j < 4; ++j) {
            const size_t m = (size_t)(mrow0 + mi * 16 + j);
            const float gi = acc[mi][0][j] + b0;
            const float gf = acc[mi][1][j] + b1;
            const float gg = acc[mi][2][j] + b2;
            const float go = acc[mi][3][j] + b3;
            float c2 = sigm(gi) * tanh_(gg);
            if (HAS_CIN) c2 += sigm(gf) * bf2f(Cin[m * H + ocol]);
            const float h2 = sigm(go) * tanh_(c2);
            if (LAST) {
                HoutF[m * H + ocol] = h2;
            } else {
                HoutB[m * H + ocol] = f2bf(h2);
                CoutB[m * H + ocol] = f2bf(c2);
            }
        }
}

// ---------------- conv1d(k=3,pad=1)+softmax, vectorized: R=2048/L rows/block
template<int L>
__global__ __launch_bounds__(256) void conv_dual(
    const unsigned short* __restrict__ Hin, const unsigned short* __restrict__ Cin,
    const float* __restrict__ w3h, const float* __restrict__ w3c,
    unsigned short* __restrict__ hbuf, unsigned short* __restrict__ cbuf)
{
    constexpr int R = 2048 / L;
    constexpr int TPR = L / 8;
    __shared__ float xs[R][L + 2];
    __shared__ float red[8];
    const int nb = gridDim.x >> 1;
    const bool isC = (int)blockIdx.x >= nb;
    const int row0 = (isC ? (int)blockIdx.x - nb : (int)blockIdx.x) * R;
    const unsigned short* Xs = isC ? Cin : Hin;
    const float* w3 = isC ? w3c : w3h;
    const int t = threadIdx.x;
    const int r = t / TPR;
    const int c8 = (t % TPR) * 8;
    const float w0 = w3[0], w1 = w3[1], w2 = w3[2];

    const u16x8 v = *(const u16x8*)(Xs + (size_t)(row0 + r) * L + c8);
#pragma unroll
    for (int k = 0; k < 8; ++k) xs[r][c8 + 1 + k] = bf2f(v[k]);
    if (t < R) { xs[t][0] = 0.f; xs[t][L + 1] = 0.f; }
    __syncthreads();

    float y[8];
    float vmax = -3.4e38f;
#pragma unroll
    for (int k = 0; k < 8; ++k) {
        y[k] = w0 * xs[r][c8 + k] + w1 * xs[r][c8 + k + 1] + w2 * xs[r][c8 + k + 2];
        vmax = fmaxf(vmax, y[k]);
    }
#pragma unroll
    for (int off = (TPR >= 64 ? 32 : TPR / 2); off >= 1; off >>= 1)
        vmax = fmaxf(vmax, __shfl_xor(vmax, off));
    if (TPR == 128) {
        if ((t & 63) == 0) red[t >> 6] = vmax;
        __syncthreads();
        vmax = fmaxf(red[2 * r], red[2 * r + 1]);
    }
    float s = 0.f;
#pragma unroll
    for (int k = 0; k < 8; ++k) { y[k] = __expf(y[k] - vmax); s += y[k]; }
#pragma unroll
    for (int off = (TPR >= 64 ? 32 : TPR / 2); off >= 1; off >>= 1)
        s += __shfl_xor(s, off);
    if (TPR == 128) {
        if ((t & 63) == 0) red[4 + (t >> 6)] = s;
        __syncthreads();
        s = red[4 + 2 * r] + red[4 + 2 * r + 1];
    }
    const float inv = 1.f / s;
    u16x8 o;
#pragma unroll
    for (int k = 0; k < 8; ++k) o[k] = f2bf(y[k] * inv);
    if (isC) *(u16x8*)(cbuf + (size_t)(row0 + r) * L + c8) = o;
    else     *(u16x8*)(hbuf + (size_t)(row0 + r) * L + c8) = o;
}

extern "C" void kernel_launch(void* const* d_in, const int* in_sizes, int n_in,
                              void* d_out, int out_size, void* d_ws, size_t ws_size,
                              hipStream_t stream)
{
    (void)in_sizes; (void)n_in; (void)out_size; (void)ws_size;
    const float* spec  = (const float*)d_in[0];
    const float* Wih1  = (const float*)d_in[1];
    const float* Whh1  = (const float*)d_in[2];
    const float* bih1  = (const float*)d_in[3];
    const float* bhh1  = (const float*)d_in[4];
    const float* Wih2  = (const float*)d_in[5];
    const float* Whh2  = (const float*)d_in[6];
    const float* bih2  = (const float*)d_in[7];
    const float* bhh2  = (const float*)d_in[8];
    const float* Wih3  = (const float*)d_in[9];
    const float* Whh3  = (const float*)d_in[10];
    const float* bih3  = (const float*)d_in[11];
    const float* bhh3  = (const float*)d_in[12];
    const float* Wih4  = (const float*)d_in[13];
    const float* bih4  = (const float*)d_in[15];
    const float* bhh4  = (const float*)d_in[16];
    const float* w2_1h = (const float*)d_in[17];
    const float* w2_1c = (const float*)d_in[18];
    const float* w3_2h = (const float*)d_in[19];
    const float* w3_2c = (const float*)d_in[20];
    const float* w4_3h = (const float*)d_in[21];
    const float* w4_3c = (const float*)d_in[22];

    char* ws = (char*)d_ws;
    // offsets verified by running sums:
    unsigned short* h   = (unsigned short*)(ws + 0);                //  8388608 -> ends  8388608
    unsigned short* c   = (unsigned short*)(ws + (size_t)8388608);  //  8388608 -> ends 16777216
    unsigned short* cb  = (unsigned short*)(ws + (size_t)16777216); //  8388608 -> ends 25165824
    unsigned short* hb  = (unsigned short*)(ws + (size_t)25165824); //  8388608 -> ends 33554432
    unsigned short* sB  = (unsigned short*)(ws + (size_t)33554432); // 16777216 -> ends 50331648
    unsigned short* Wc1 = (unsigned short*)(ws + (size_t)50331648); // 25165824 -> ends 75497472
    unsigned short* Wc2 = (unsigned short*)(ws + (size_t)75497472); //  6291456 -> ends 81788928
    unsigned short* Wc3 = (unsigned short*)(ws + (size_t)81788928); //  1572864 -> ends 83361792
    unsigned short* W4  = (unsigned short*)(ws + (size_t)83361792); //   262144 -> ends 83623936
    float*          bs1 = (float*)(ws + (size_t)83623936);
    float*          bs2 = bs1 + 4096;
    float*          bs3 = bs2 + 4096;
    float*          bs4 = bs3 + 4096;

    // ---- merged prep (Whh4 unused: level-4 h_in == 0)
    PArgs pa;
    pa.s[0] = { Wih1, Wc1,       0, 1024, 9, 3072,    0 };
    pa.s[1] = { Whh1, Wc1, 2097152, 1024, 8, 3072, 2048 };
    pa.s[2] = { Wih2, Wc2, 3145728,  512, 8, 1536,    0 };
    pa.s[3] = { Whh2, Wc2, 3670016,  512, 7, 1536, 1024 };
    pa.s[4] = { Wih3, Wc3, 3932160,  256, 7,  768,    0 };
    pa.s[5] = { Whh3, Wc3, 4063232,  256, 6,  768,  512 };
    pa.s[6] = { Wih4, W4,  4128768,  128, 6,  256,    0 };
    pa.spec = spec; pa.sB = sB;
    pa.bi1 = bih1; pa.bh1 = bhh1; pa.bi2 = bih2; pa.bh2 = bhh2;
    pa.bi3 = bih3; pa.bh3 = bhh3; pa.bi4 = bih4; pa.bh4 = bhh4;
    pa.bs1 = bs1; pa.bs2 = bs2; pa.bs3 = bs3; pa.bs4 = bs4;
    prep_all<<<2048, 256, 0, stream>>>(pa);

    // ---- Level 4: M=32768, N=512 (H=128), K=256 (A0 = sB as [32768,256])
    gemm16<false, false><<<dim3(128, 2), 1024, 0, stream>>>(
        sB, nullptr, 256, 0, W4, bs4, nullptr, nullptr, h, c, 128);
    conv_dual<256><<<4096, 256, 0, stream>>>(h, c, w4_3h, w4_3c, hb, cb);

    // ---- Level 3: M=16384, N=1024 (H=256), K=512+256
    gemm16<true, false><<<dim3(64, 4), 1024, 0, stream>>>(
        sB, hb, 512, 256, Wc3, bs3, cb, nullptr, h, c, 256);
    conv_dual<512><<<4096, 256, 0, stream>>>(h, c, w3_2h, w3_2c, hb, cb);

    // ---- Level 2: M=8192, N=2048 (H=512), K=1024+512
    gemm16<true, false><<<dim3(32, 8), 1024, 0, stream>>>(
        sB, hb, 1024, 512, Wc2, bs2, cb, nullptr, h, c, 512);
    conv_dual<1024><<<4096, 256, 0, stream>>>(h, c, w2_1h, w2_1c, hb, cb);

    // ---- Level 1: M=4096, N=4096 (H=1024), K=2048+1024; h1 -> d_out (f32)
    gemm16<true, true><<<dim3(16, 16), 1024, 0, stream>>>(
        sB, hb, 2048, 1024, Wc1, bs1, cb, (float*)d_out, nullptr, nullptr, 1024);
}

// Round 18
// 269.249 us; speedup vs baseline: 1.9417x; 1.9417x over previous
//
#include <hip/hip_runtime.h>

// B=4096, ID=2048, OD=1024. 4-level pyramidal LSTM, f32 I/O.
// FINAL (= r14, best measured 271.4us): GEMM = 256x256 tile, 8 waves (2/SIMD),
// 2-phase counted-vmcnt(4) K-loop (r8 schedule), T1 XCD swizzle, T2 LDS
// swizzle (conflicts=0), T5 setprio. Two-segment A (A0=flat bf16 spec
// reinterpreted per level, A1=compact hb). LSTM cell fused into the GEMM
// epilogue via gate-interleaved weight permutation
// (W row p <- orig q*H+o, p = 64*(o>>4) + 16*q + (o&15)) -> lane-local gates.
// bf16 h/c/cb/hb intermediates. prep_all = spec-cvt + weight-perm + bias.

typedef __bf16 bf16x8 __attribute__((ext_vector_type(8)));
typedef float f32x4 __attribute__((ext_vector_type(4)));
typedef unsigned short u16x4 __attribute__((ext_vector_type(4)));
typedef unsigned short u16x8 __attribute__((ext_vector_type(8)));

#define AS1 __attribute__((address_space(1)))
#define AS3 __attribute__((address_space(3)))

__device__ __forceinline__ unsigned short f2bf(float f) {
    union { float f; unsigned int i; } v; v.f = f;
    unsigned int r = v.i + 0x7fffu + ((v.i >> 16) & 1u);
    return (unsigned short)(r >> 16);
}
__device__ __forceinline__ float bf2f(unsigned short u) {
    union { unsigned int i; float f; } v; v.i = ((unsigned int)u) << 16; return v.f;
}
__device__ __forceinline__ float sigm(float x) { return 1.f / (1.f + __expf(-x)); }
__device__ __forceinline__ float tanh_(float x) { float e = __expf(2.f * x); return 1.f - 2.f / (e + 1.f); }

// ---------------- merged prep: spec f32->bf16 | weight convert+gate-permute | biases
struct PSeg { const float* src; unsigned short* dst; long g0; int H; int kshift; int dstld; int dstcol; };
struct PArgs {
    PSeg s[7];
    const float* spec; unsigned short* sB;
    const float *bi1, *bh1, *bi2, *bh2, *bi3, *bh3, *bi4, *bh4;
    float *bs1, *bs2, *bs3, *bs4;
};

__global__ __launch_bounds__(256) void prep_all(PArgs pa)
{
    const long NS = 2097152;              // spec u16x4 granules (4096*2048/4)
    const long NP = 4161536;              // permW granules
    const long total = NS + NP + 7680;    // + bias elements
    const long stride = (long)gridDim.x * blockDim.x;
    for (long gi = (long)blockIdx.x * blockDim.x + threadIdx.x; gi < total; gi += stride) {
        if (gi < NS) {
            const float4 v = ((const float4*)pa.spec)[gi];
            u16x4 o; o.x = f2bf(v.x); o.y = f2bf(v.y); o.z = f2bf(v.z); o.w = f2bf(v.w);
            ((u16x4*)pa.sB)[gi] = o;
        } else if (gi < NS + NP) {
            const long gp = gi - NS;
            int si = 0;
#pragma unroll
            for (int k = 1; k < 7; ++k) si += (gp >= pa.s[k].g0);
            const PSeg sg = pa.s[si];
            const long i = gp - sg.g0;
            const int kq = 1 << sg.kshift;
            const int p = (int)(i >> sg.kshift);
            const int kk = ((int)i & (kq - 1)) << 2;
            const int o = ((p >> 6) << 4) | (p & 15);
            const int q = (p >> 4) & 3;
            const long r = (long)q * sg.H + o;
            const float4 v = *(const float4*)(sg.src + (r << (sg.kshift + 2)) + kk);
            u16x4 wv; wv.x = f2bf(v.x); wv.y = f2bf(v.y); wv.z = f2bf(v.z); wv.w = f2bf(v.w);
            *(u16x4*)(sg.dst + (long)p * sg.dstld + sg.dstcol + kk) = wv;
        } else {
            const int i = (int)(gi - NS - NP);
            const float *bih, *bhh; float* dst; int H, j;
            if (i < 4096)      { bih = pa.bi1; bhh = pa.bh1; dst = pa.bs1; H = 1024; j = i; }
            else if (i < 6144) { bih = pa.bi2; bhh = pa.bh2; dst = pa.bs2; H = 512;  j = i - 4096; }
            else if (i < 7168) { bih = pa.bi3; bhh = pa.bh3; dst = pa.bs3; H = 256;  j = i - 6144; }
            else               { bih = pa.bi4; bhh = pa.bh4; dst = pa.bs4; H = 128;  j = i - 7168; }
            const int o = ((j >> 6) << 4) | (j & 15);
            const int q = (j >> 4) & 3;
            dst[j] = bih[q * H + o] + bhh[q * H + o];
        }
    }
}

// ---------------- 256x256 fused GEMM+LSTM-cell (r8 structure, two-segment A)
#define QUAD(AF, S, NS_, BF)                                                                \
    { _Pragma("unroll") for (int mi = 0; mi < 4; ++mi) {                                    \
        _Pragma("unroll") for (int ni = 0; ni < 2; ++ni) {                                  \
            acc[(S)*4+mi][(NS_)*2+ni] = __builtin_amdgcn_mfma_f32_16x16x32_bf16(            \
                AF[mi][0], BF[ni][0], acc[(S)*4+mi][(NS_)*2+ni], 0, 0, 0);                  \
            acc[(S)*4+mi][(NS_)*2+ni] = __builtin_amdgcn_mfma_f32_16x16x32_bf16(            \
                AF[mi][1], BF[ni][1], acc[(S)*4+mi][(NS_)*2+ni], 0, 0, 0);                  \
    } } }

#define GLL(gsrc, loff) __builtin_amdgcn_global_load_lds(                                   \
    (const AS1 void*)(gsrc), (AS3 void*)(lds + (loff)), 16, 0, 0)

#define FENCE asm volatile("" ::: "memory")

// stage the 2 halves of A K-tile tts into LDS buffer qq (segment-selected)
#define STAGE_A(tts, qq)                                                                    \
    { if ((tts) < nk0) {                                                                    \
        const size_t ko = (size_t)(tts) * 64;                                               \
        GLL(A0 + a0off0 + ko, ((qq) << 16) + sd0);                                          \
        GLL(A0 + a0off1 + ko, ((qq) << 16) + sd1);                                          \
        GLL(A0 + a0off0 + k128_0 + ko, ((qq) << 16) + 16384 + sd0);                         \
        GLL(A0 + a0off1 + k128_0 + ko, ((qq) << 16) + 16384 + sd1);                         \
    } else {                                                                                \
        const size_t ko = (size_t)((tts) - nk0) * 64;                                       \
        GLL(A1 + a1off0 + ko, ((qq) << 16) + sd0);                                          \
        GLL(A1 + a1off1 + ko, ((qq) << 16) + sd1);                                          \
        GLL(A1 + a1off0 + k128_1 + ko, ((qq) << 16) + 16384 + sd0);                         \
        GLL(A1 + a1off1 + k128_1 + ko, ((qq) << 16) + 16384 + sd1);                         \
    } }

template<bool HAS_CIN, bool LAST>
__global__ __launch_bounds__(512, 2) void gemm8(
    const unsigned short* __restrict__ A0, const unsigned short* __restrict__ A1,
    const int K0, const int K1,
    const unsigned short* __restrict__ W,
    const float* __restrict__ bsum, const unsigned short* __restrict__ Cin,
    float* __restrict__ HoutF, unsigned short* __restrict__ HoutB,
    unsigned short* __restrict__ CoutB, const int H)
{
    __shared__ __align__(16) char lds[131072];
    const int t = threadIdx.x;
    const int w = t >> 6, l = t & 63;
    const int wr = w >> 2, wc = w & 3;                 // 2m x 4n wave grid
    const int K = K0 + K1;
    const int nk0 = K0 >> 6;

    const int GX = gridDim.x, GY = gridDim.y;
    const int nwg = GX * GY;
    const int bid = (int)blockIdx.y * GX + (int)blockIdx.x;
    const int swz = (bid & 7) * (nwg >> 3) + (bid >> 3);
    const int m0 = (swz / GY) * 256, n0 = (swz % GY) * 256;

    const int colsw = ((l & 7) ^ (l >> 3)) * 8;        // swizzled source col granule
    const int arow = m0 + w * 16 + (l >> 3);
    const size_t a0off0 = (size_t)arow * K0 + colsw;
    const size_t a0off1 = a0off0 + (size_t)8 * K0;
    const size_t a1off0 = (size_t)arow * K1 + colsw;
    const size_t a1off1 = a1off0 + (size_t)8 * K1;
    const size_t k128_0 = (size_t)128 * K0;
    const size_t k128_1 = (size_t)128 * K1;
    const size_t k128 = (size_t)128 * K;
    const size_t boff0 = (size_t)(n0 + w * 16 + (l >> 3)) * K + colsw;
    const size_t boff1 = boff0 + (size_t)8 * K;
    const int sd0 = w * 2048 + l * 16;                 // LDS byte dest (within region)
    const int sd1 = sd0 + 1024;

    const int lr128 = (l & 15) * 128;
    const int sw0 = (((l >> 4)    ) ^ (l & 7)) * 16;   // swizzled ds_read granules
    const int sw1 = (((l >> 4) + 4) ^ (l & 7)) * 16;

    f32x4 acc[8][4];
#pragma unroll
    for (int i = 0; i < 8; ++i)
#pragma unroll
        for (int j = 0; j < 4; ++j) acc[i][j] = (f32x4){0.f, 0.f, 0.f, 0.f};

    const int NT = K >> 6;   // prologue tiles 0,1 in seg0 (nk0 >= 4 for all levels)

    STAGE_A(0, 0);
    GLL(W + boff0, 32768 + sd0);              GLL(W + boff1, 32768 + sd1);
    GLL(W + boff0 + k128, 49152 + sd0);       GLL(W + boff1 + k128, 49152 + sd1);
    GLL(W + boff0 + 64, 98304 + sd0);         GLL(W + boff1 + 64, 98304 + sd1);
    GLL(W + boff0 + k128 + 64, 114688 + sd0); GLL(W + boff1 + k128 + 64, 114688 + sd1);

    bf16x8 aLo[4][2], aHi[4][2], bF0[2][2], bF1[2][2];

    for (int tt = 0; tt < NT; ++tt) {
        const int q = tt & 1, qn = q ^ 1;
        const int rbA = (q << 16) + (wr << 14) + lr128;
        const int rbB = (q << 16) + 32768 + wc * 8192 + lr128;
        const bool st1 = (tt + 1 < NT), st2 = (tt + 2 < NT);

        if (st1) { asm volatile("s_waitcnt vmcnt(4)" ::: "memory"); }
        else     { asm volatile("s_waitcnt vmcnt(0)" ::: "memory"); }
        __builtin_amdgcn_s_barrier();
        FENCE;

#pragma unroll
        for (int mi = 0; mi < 4; ++mi) {
            aLo[mi][0] = *(const bf16x8*)(lds + rbA + mi * 2048 + sw0);
            aLo[mi][1] = *(const bf16x8*)(lds + rbA + mi * 2048 + sw1);
        }
#pragma unroll
        for (int ni = 0; ni < 2; ++ni) {
            bF0[ni][0] = *(const bf16x8*)(lds + rbB + ni * 2048 + sw0);
            bF0[ni][1] = *(const bf16x8*)(lds + rbB + ni * 2048 + sw1);
            bF1[ni][0] = *(const bf16x8*)(lds + rbB + 4096 + ni * 2048 + sw0);
            bF1[ni][1] = *(const bf16x8*)(lds + rbB + 4096 + ni * 2048 + sw1);
        }
        if (st1) { STAGE_A(tt + 1, qn); }
#pragma unroll
        for (int mi = 0; mi < 4; ++mi) {
            aHi[mi][0] = *(const bf16x8*)(lds + rbA + 8192 + mi * 2048 + sw0);
            aHi[mi][1] = *(const bf16x8*)(lds + rbA + 8192 + mi * 2048 + sw1);
        }

        __builtin_amdgcn_s_setprio(1);
        QUAD(aLo, 0, 0, bF0);
        QUAD(aLo, 0, 1, bF1);
        __builtin_amdgcn_s_setprio(0);
        __builtin_amdgcn_s_barrier();
        FENCE;

        if (st2) {
            const size_t ko2 = (size_t)(tt + 2) * 64;
            GLL(W + boff0 + ko2, (q << 16) + 32768 + sd0);
            GLL(W + boff1 + ko2, (q << 16) + 32768 + sd1);
            GLL(W + boff0 + k128 + ko2, (q << 16) + 49152 + sd0);
            GLL(W + boff1 + k128 + ko2, (q << 16) + 49152 + sd1);
        }
        __builtin_amdgcn_s_setprio(1);
        QUAD(aHi, 1, 1, bF1);
        QUAD(aHi, 1, 0, bF0);
        __builtin_amdgcn_s_setprio(0);
    }

    // ---- fused LSTM-cell epilogue
    const int ocol = (n0 >> 6) * 16 + wc * 16 + (l & 15);
    const int bb = n0 + wc * 64 + (l & 15);
    const float b0 = bsum[bb], b1 = bsum[bb + 16], b2 = bsum[bb + 32], b3 = bsum[bb + 48];
    const int mrow0 = m0 + wr * 128 + (l >> 4) * 4;
#pragma unroll
    for (int mi = 0; mi < 8; ++mi)
#pragma unroll
        for (int j = 0; j < 4; ++j) {
            const size_t m = (size_t)(mrow0 + mi * 16 + j);
            const float gi = acc[mi][0][j] + b0;
            const float gf = acc[mi][1][j] + b1;
            const float gg = acc[mi][2][j] + b2;
            const float go = acc[mi][3][j] + b3;
            float c2 = sigm(gi) * tanh_(gg);
            if (HAS_CIN) c2 += sigm(gf) * bf2f(Cin[m * H + ocol]);
            const float h2 = sigm(go) * tanh_(c2);
            if (LAST) {
                HoutF[m * H + ocol] = h2;
            } else {
                HoutB[m * H + ocol] = f2bf(h2);
                CoutB[m * H + ocol] = f2bf(c2);
            }
        }
}

// ---------------- conv1d(k=3,pad=1)+softmax, vectorized: R=2048/L rows/block
// blocks [0, nb): h -> hbuf (compact); [nb, 2nb): c -> cbuf (compact)
template<int L>
__global__ __launch_bounds__(256) void conv_dual(
    const unsigned short* __restrict__ Hin, const unsigned short* __restrict__ Cin,
    const float* __restrict__ w3h, const float* __restrict__ w3c,
    unsigned short* __restrict__ hbuf, unsigned short* __restrict__ cbuf)
{
    constexpr int R = 2048 / L;          // rows per block
    constexpr int TPR = L / 8;           // threads per row (32 / 64 / 128)
    __shared__ float xs[R][L + 2];
    __shared__ float red[8];
    const int nb = gridDim.x >> 1;
    const bool isC = (int)blockIdx.x >= nb;
    const int row0 = (isC ? (int)blockIdx.x - nb : (int)blockIdx.x) * R;
    const unsigned short* Xs = isC ? Cin : Hin;
    const float* w3 = isC ? w3c : w3h;
    const int t = threadIdx.x;
    const int r = t / TPR;
    const int c8 = (t % TPR) * 8;
    const float w0 = w3[0], w1 = w3[1], w2 = w3[2];

    const u16x8 v = *(const u16x8*)(Xs + (size_t)(row0 + r) * L + c8);
#pragma unroll
    for (int k = 0; k < 8; ++k) xs[r][c8 + 1 + k] = bf2f(v[k]);
    if (t < R) { xs[t][0] = 0.f; xs[t][L + 1] = 0.f; }
    __syncthreads();

    float y[8];
    float vmax = -3.4e38f;
#pragma unroll
    for (int k = 0; k < 8; ++k) {
        y[k] = w0 * xs[r][c8 + k] + w1 * xs[r][c8 + k + 1] + w2 * xs[r][c8 + k + 2];
        vmax = fmaxf(vmax, y[k]);
    }
#pragma unroll
    for (int off = (TPR >= 64 ? 32 : TPR / 2); off >= 1; off >>= 1)
        vmax = fmaxf(vmax, __shfl_xor(vmax, off));
    if (TPR == 128) {                    // combine the row's two waves
        if ((t & 63) == 0) red[t >> 6] = vmax;
        __syncthreads();
        vmax = fmaxf(red[2 * r], red[2 * r + 1]);
    }
    float s = 0.f;
#pragma unroll
    for (int k = 0; k < 8; ++k) { y[k] = __expf(y[k] - vmax); s += y[k]; }
#pragma unroll
    for (int off = (TPR >= 64 ? 32 : TPR / 2); off >= 1; off >>= 1)
        s += __shfl_xor(s, off);
    if (TPR == 128) {
        if ((t & 63) == 0) red[4 + (t >> 6)] = s;
        __syncthreads();
        s = red[4 + 2 * r] + red[4 + 2 * r + 1];
    }
    const float inv = 1.f / s;
    u16x8 o;
#pragma unroll
    for (int k = 0; k < 8; ++k) o[k] = f2bf(y[k] * inv);
    if (isC) *(u16x8*)(cbuf + (size_t)(row0 + r) * L + c8) = o;
    else     *(u16x8*)(hbuf + (size_t)(row0 + r) * L + c8) = o;
}

extern "C" void kernel_launch(void* const* d_in, const int* in_sizes, int n_in,
                              void* d_out, int out_size, void* d_ws, size_t ws_size,
                              hipStream_t stream)
{
    (void)in_sizes; (void)n_in; (void)out_size; (void)ws_size;
    const float* spec  = (const float*)d_in[0];
    const float* Wih1  = (const float*)d_in[1];
    const float* Whh1  = (const float*)d_in[2];
    const float* bih1  = (const float*)d_in[3];
    const float* bhh1  = (const float*)d_in[4];
    const float* Wih2  = (const float*)d_in[5];
    const float* Whh2  = (const float*)d_in[6];
    const float* bih2  = (const float*)d_in[7];
    const float* bhh2  = (const float*)d_in[8];
    const float* Wih3  = (const float*)d_in[9];
    const float* Whh3  = (const float*)d_in[10];
    const float* bih3  = (const float*)d_in[11];
    const float* bhh3  = (const float*)d_in[12];
    const float* Wih4  = (const float*)d_in[13];
    const float* bih4  = (const float*)d_in[15];
    const float* bhh4  = (const float*)d_in[16];
    const float* w2_1h = (const float*)d_in[17];
    const float* w2_1c = (const float*)d_in[18];
    const float* w3_2h = (const float*)d_in[19];
    const float* w3_2c = (const float*)d_in[20];
    const float* w4_3h = (const float*)d_in[21];
    const float* w4_3c = (const float*)d_in[22];

    char* ws = (char*)d_ws;
    // offsets verified by running sums:
    unsigned short* h   = (unsigned short*)(ws + 0);                //  8388608 -> ends  8388608
    unsigned short* c   = (unsigned short*)(ws + (size_t)8388608);  //  8388608 -> ends 16777216
    unsigned short* cb  = (unsigned short*)(ws + (size_t)16777216); //  8388608 -> ends 25165824
    unsigned short* hb  = (unsigned short*)(ws + (size_t)25165824); //  8388608 -> ends 33554432
    unsigned short* sB  = (unsigned short*)(ws + (size_t)33554432); // 16777216 -> ends 50331648
    unsigned short* Wc1 = (unsigned short*)(ws + (size_t)50331648); // 25165824 -> ends 75497472
    unsigned short* Wc2 = (unsigned short*)(ws + (size_t)75497472); //  6291456 -> ends 81788928
    unsigned short* Wc3 = (unsigned short*)(ws + (size_t)81788928); //  1572864 -> ends 83361792
    unsigned short* W4  = (unsigned short*)(ws + (size_t)83361792); //   262144 -> ends 83623936
    float*          bs1 = (float*)(ws + (size_t)83623936);
    float*          bs2 = bs1 + 4096;
    float*          bs3 = bs2 + 4096;
    float*          bs4 = bs3 + 4096;

    // ---- merged prep (Whh4 unused: level-4 h_in == 0)
    PArgs pa;
    pa.s[0] = { Wih1, Wc1,       0, 1024, 9, 3072,    0 };
    pa.s[1] = { Whh1, Wc1, 2097152, 1024, 8, 3072, 2048 };
    pa.s[2] = { Wih2, Wc2, 3145728,  512, 8, 1536,    0 };
    pa.s[3] = { Whh2, Wc2, 3670016,  512, 7, 1536, 1024 };
    pa.s[4] = { Wih3, Wc3, 3932160,  256, 7,  768,    0 };
    pa.s[5] = { Whh3, Wc3, 4063232,  256, 6,  768,  512 };
    pa.s[6] = { Wih4, W4,  4128768,  128, 6,  256,    0 };
    pa.spec = spec; pa.sB = sB;
    pa.bi1 = bih1; pa.bh1 = bhh1; pa.bi2 = bih2; pa.bh2 = bhh2;
    pa.bi3 = bih3; pa.bh3 = bhh3; pa.bi4 = bih4; pa.bh4 = bhh4;
    pa.bs1 = bs1; pa.bs2 = bs2; pa.bs3 = bs3; pa.bs4 = bs4;
    prep_all<<<2048, 256, 0, stream>>>(pa);

    // ---- Level 4: M=32768, N=512 (H=128), K=256 (A0 = sB as [32768,256])
    gemm8<false, false><<<dim3(128, 2), 512, 0, stream>>>(
        sB, nullptr, 256, 0, W4, bs4, nullptr, nullptr, h, c, 128);
    conv_dual<256><<<4096, 256, 0, stream>>>(h, c, w4_3h, w4_3c, hb, cb);

    // ---- Level 3: M=16384, N=1024 (H=256), K=512+256 (A0 = sB as [16384,512])
    gemm8<true, false><<<dim3(64, 4), 512, 0, stream>>>(
        sB, hb, 512, 256, Wc3, bs3, cb, nullptr, h, c, 256);
    conv_dual<512><<<4096, 256, 0, stream>>>(h, c, w3_2h, w3_2c, hb, cb);

    // ---- Level 2: M=8192, N=2048 (H=512), K=1024+512 (A0 = sB as [8192,1024])
    gemm8<true, false><<<dim3(32, 8), 512, 0, stream>>>(
        sB, hb, 1024, 512, Wc2, bs2, cb, nullptr, h, c, 512);
    conv_dual<1024><<<4096, 256, 0, stream>>>(h, c, w2_1h, w2_1c, hb, cb);

    // ---- Level 1: M=4096, N=4096 (H=1024), K=2048+1024; h1 -> d_out (f32)
    gemm8<true, true><<<dim3(16, 16), 512, 0, stream>>>(
        sB, hb, 2048, 1024, Wc1, bs1, cb, (float*)d_out, nullptr, nullptr, 1024);
}